// Round 4
// baseline (466.439 us; speedup 1.0000x reference)
//
#include <hip/hip_runtime.h>
#include <stdint.h>

#define T_TOK 2048
#define DIM   2048
#define FDIM  1024
#define NE    8
#define MAXTILES 40

typedef __attribute__((ext_vector_type(8))) short short8;
typedef __attribute__((ext_vector_type(4))) float f32x4;

__device__ __forceinline__ unsigned short f2b(float f) {
  union { float f; unsigned int i; } x; x.f = f;
  unsigned int r = x.i + 0x7fffu + ((x.i >> 16) & 1u);
  return (unsigned short)(r >> 16);
}

__device__ __forceinline__ void async16(void* lds, const void* g) {
  __builtin_amdgcn_global_load_lds(
      (const __attribute__((address_space(1))) void*)g,
      (__attribute__((address_space(3))) void*)lds, 16, 0, 0);
}

// ---------------- fp32 -> bf16 streaming convert (8 elems/thread) ----------------
__global__ __launch_bounds__(256) void cvt_k(const float* __restrict__ in,
                                             unsigned short* __restrict__ out)
{
  size_t i = ((size_t)blockIdx.x * 256 + threadIdx.x) * 8;
  float4 a = *(const float4*)(in + i);
  float4 b = *(const float4*)(in + i + 4);
  ushort4 o0, o1;
  o0.x = f2b(a.x); o0.y = f2b(a.y); o0.z = f2b(a.z); o0.w = f2b(a.w);
  o1.x = f2b(b.x); o1.y = f2b(b.y); o1.z = f2b(b.z); o1.w = f2b(b.w);
  *(ushort4*)(out + i) = o0;
  *(ushort4*)(out + i + 4) = o1;
}

// ---------------- router: fp32 logits, softmax, top-2, renorm ----------------
__global__ __launch_bounds__(256) void router_k(
    const float* __restrict__ x, const float* __restrict__ gw,
    float* __restrict__ topkw, int* __restrict__ topke, int* __restrict__ counts,
    float* __restrict__ logits_out)
{
  int wave = threadIdx.x >> 6, lane = threadIdx.x & 63;
  int t = blockIdx.x * 4 + wave;
  const float* xr = x + (size_t)t * DIM;
  float acc[NE];
#pragma unroll
  for (int e = 0; e < NE; e++) acc[e] = 0.f;
  for (int d = lane * 4; d < DIM; d += 256) {
    float4 xv = *(const float4*)(xr + d);
#pragma unroll
    for (int e = 0; e < NE; e++) {
      float4 gv = *(const float4*)(gw + e * DIM + d);
      acc[e] += xv.x * gv.x + xv.y * gv.y + xv.z * gv.z + xv.w * gv.w;
    }
  }
#pragma unroll
  for (int off = 32; off > 0; off >>= 1) {
#pragma unroll
    for (int e = 0; e < NE; e++) acc[e] += __shfl_down(acc[e], off);
  }
  if (lane == 0) {
    float m = acc[0];
#pragma unroll
    for (int e = 1; e < NE; e++) m = fmaxf(m, acc[e]);
    float p[NE];
#pragma unroll
    for (int e = 0; e < NE; e++) p[e] = __expf(acc[e] - m);
    int e0 = 0;
#pragma unroll
    for (int e = 1; e < NE; e++) if (acc[e] > acc[e0]) e0 = e;
    int e1 = -1;
#pragma unroll
    for (int e = 0; e < NE; e++) if (e != e0 && (e1 < 0 || acc[e] > acc[e1])) e1 = e;
    float s = p[e0] + p[e1];
    topkw[t * 2] = p[e0] / s;
    topkw[t * 2 + 1] = p[e1] / s;
    topke[t * 2] = e0; topke[t * 2 + 1] = e1;
    atomicAdd(&counts[e0], 1);
    atomicAdd(&counts[e1], 1);
#pragma unroll
    for (int e = 0; e < NE; e++) logits_out[t * NE + e] = acc[e];
  }
}

// ---------------- scan: offsets, cursors, tile table ----------------
__global__ void scan_k(const int* __restrict__ counts, int* __restrict__ offsets,
                       int* __restrict__ cursors, int4* __restrict__ tiles,
                       int* __restrict__ ntiles)
{
  if (threadIdx.x == 0 && blockIdx.x == 0) {
    int o = 0, nt = 0;
    for (int e = 0; e < NE; e++) {
      offsets[e] = o; cursors[e] = o;
      int c = counts[e];
      for (int r = 0; r < c; r += 128) {
        int rows = c - r < 128 ? c - r : 128;
        tiles[nt] = make_int4(e, o + r, rows, 0);
        nt++;
      }
      o += c;
    }
    offsets[NE] = o;
    *ntiles = nt;
  }
}

// ---------------- scatter: (t,k) -> sorted slot ----------------
__global__ void scatter_k(const int* __restrict__ topke, int* __restrict__ cursors,
                          int* __restrict__ perm)
{
  int i = blockIdx.x * blockDim.x + threadIdx.x;
  int e = topke[i];
  int s = atomicAdd(&cursors[e], 1);
  perm[s] = i;
}

// ---------------- GEMM1: H[slot,f] = rw * silu(x@Wg^T) * (x@Wu^T) ----------------
// BM=128, BN=64, BK=64. CVT: B pre-converted bf16 via async16. !CVT: fp32 B
// loads converted in-register.
template <bool CVT>
__global__ __launch_bounds__(256) void gemm1_k(
    const unsigned short* __restrict__ xb,
    const unsigned short* __restrict__ wgb,
    const unsigned short* __restrict__ wub,
    const float* __restrict__ wg32,
    const float* __restrict__ wu32,
    const int* __restrict__ perm, const float* __restrict__ topkw,
    const int4* __restrict__ tiles, const int* __restrict__ ntiles,
    unsigned short* __restrict__ H)
{
  __shared__ short As[128 * 64];
  __shared__ short Bgs[64 * 64];
  __shared__ short Bus[64 * 64];
  __shared__ int rowtok[128];
  __shared__ float roww[128];

  if (blockIdx.x >= *ntiles) return;
  int4 tm = tiles[blockIdx.x];
  int e = tm.x, row0 = tm.y, nrows = tm.z;
  int tid = threadIdx.x;
  if (tid < 128) {
    int r = tid < nrows ? tid : (nrows - 1);
    int pid = perm[row0 + r];
    rowtok[tid] = pid >> 1;
    roww[tid] = topkw[pid];
  }
  __syncthreads();

  int f0 = blockIdx.y * 64;
  int sub = tid & 7;       // 8-elem chunk within a 64-elem row
  int srow = tid >> 3;     // 0..31

  const unsigned short* ag[4];
#pragma unroll
  for (int c = 0; c < 4; c++)
    ag[c] = xb + (size_t)rowtok[c * 32 + srow] * DIM + sub * 8;

  const unsigned short *bg[2], *bu[2];
  const float *bg32[2], *bu32[2];
#pragma unroll
  for (int c = 0; c < 2; c++) {
    size_t row = (size_t)e * FDIM + f0 + c * 32 + srow;
    if (CVT) {
      bg[c] = wgb + row * DIM + sub * 8;
      bu[c] = wub + row * DIM + sub * 8;
    } else {
      bg32[c] = wg32 + row * DIM + sub * 8;
      bu32[c] = wu32 + row * DIM + sub * 8;
    }
  }

  int wave = tid >> 6, lane = tid & 63;
  int wm = wave >> 1, wn = wave & 1;
  int lrow = lane & 15, quad = lane >> 4;

  f32x4 accg[4][2], accu[4][2];
#pragma unroll
  for (int i = 0; i < 4; i++)
#pragma unroll
    for (int j = 0; j < 2; j++) {
      accg[i][j] = (f32x4){0.f, 0.f, 0.f, 0.f};
      accu[i][j] = (f32x4){0.f, 0.f, 0.f, 0.f};
    }

  const short* arp = As + (wm * 64 + lrow) * 64 + quad * 8;
  const short* bgp = Bgs + (wn * 32 + lrow) * 64 + quad * 8;
  const short* bup = Bus + (wn * 32 + lrow) * 64 + quad * 8;

#pragma unroll 1
  for (int k0 = 0; k0 < DIM; k0 += 64) {
#pragma unroll
    for (int c = 0; c < 4; c++) async16(As + c * 2048 + tid * 8, ag[c] + k0);
    if (CVT) {
#pragma unroll
      for (int c = 0; c < 2; c++) {
        async16(Bgs + c * 2048 + tid * 8, bg[c] + k0);
        async16(Bus + c * 2048 + tid * 8, bu[c] + k0);
      }
    } else {
#pragma unroll
      for (int c = 0; c < 2; c++) {
        float4 g0 = *(const float4*)(bg32[c] + k0);
        float4 g1 = *(const float4*)(bg32[c] + k0 + 4);
        float4 u0 = *(const float4*)(bu32[c] + k0);
        float4 u1 = *(const float4*)(bu32[c] + k0 + 4);
        short8 gs, us;
        gs[0] = f2b(g0.x); gs[1] = f2b(g0.y); gs[2] = f2b(g0.z); gs[3] = f2b(g0.w);
        gs[4] = f2b(g1.x); gs[5] = f2b(g1.y); gs[6] = f2b(g1.z); gs[7] = f2b(g1.w);
        us[0] = f2b(u0.x); us[1] = f2b(u0.y); us[2] = f2b(u0.z); us[3] = f2b(u0.w);
        us[4] = f2b(u1.x); us[5] = f2b(u1.y); us[6] = f2b(u1.z); us[7] = f2b(u1.w);
        *(short8*)(Bgs + c * 2048 + tid * 8) = gs;
        *(short8*)(Bus + c * 2048 + tid * 8) = us;
      }
    }
    __syncthreads();
#pragma unroll
    for (int s = 0; s < 2; s++) {
      short8 af[4], bgf[2], buf2[2];
#pragma unroll
      for (int i = 0; i < 4; i++) af[i] = *(const short8*)(arp + i * 16 * 64 + s * 32);
#pragma unroll
      for (int j = 0; j < 2; j++) {
        bgf[j]  = *(const short8*)(bgp + j * 16 * 64 + s * 32);
        buf2[j] = *(const short8*)(bup + j * 16 * 64 + s * 32);
      }
#pragma unroll
      for (int i = 0; i < 4; i++)
#pragma unroll
        for (int j = 0; j < 2; j++) {
          accg[i][j] = __builtin_amdgcn_mfma_f32_16x16x32_bf16(af[i], bgf[j], accg[i][j], 0, 0, 0);
          accu[i][j] = __builtin_amdgcn_mfma_f32_16x16x32_bf16(af[i], buf2[j], accu[i][j], 0, 0, 0);
        }
    }
    __syncthreads();
  }

#pragma unroll
  for (int i = 0; i < 4; i++) {
#pragma unroll
    for (int reg = 0; reg < 4; reg++) {
      int r = wm * 64 + i * 16 + quad * 4 + reg;
      if (r < nrows) {
        float w = roww[r];
#pragma unroll
        for (int j = 0; j < 2; j++) {
          float g = accg[i][j][reg], u = accu[i][j][reg];
          float h = g * u * w / (1.f + __expf(-g));
          H[(size_t)(row0 + r) * FDIM + f0 + wn * 32 + j * 16 + lrow] = f2b(h);
        }
      }
    }
  }
}

// ---------------- GEMM2: out[t,d] += H[slot,:] @ Wd[e]^T  (fp32 atomics) ----------------
template <bool CVT>
__global__ __launch_bounds__(256) void gemm2_k(
    const unsigned short* __restrict__ H,
    const unsigned short* __restrict__ wdb,
    const float* __restrict__ wd32,
    const int* __restrict__ perm,
    const int4* __restrict__ tiles, const int* __restrict__ ntiles,
    float* __restrict__ out)
{
  __shared__ short Hs[128 * 64];
  __shared__ short Bs[64 * 64];
  __shared__ int rowtok[128];

  if (blockIdx.x >= *ntiles) return;
  int4 tm = tiles[blockIdx.x];
  int e = tm.x, row0 = tm.y, nrows = tm.z;
  int tid = threadIdx.x;
  if (tid < 128) {
    int r = tid < nrows ? tid : (nrows - 1);
    rowtok[tid] = perm[row0 + r] >> 1;
  }
  __syncthreads();

  int d0 = blockIdx.y * 64;
  int sub = tid & 7, srow = tid >> 3;

  const unsigned short* ah[4];
#pragma unroll
  for (int c = 0; c < 4; c++)
    ah[c] = H + (size_t)(row0 + c * 32 + srow) * FDIM + sub * 8;

  const unsigned short* bw[2];
  const float* bw32[2];
#pragma unroll
  for (int c = 0; c < 2; c++) {
    size_t row = (size_t)e * DIM + d0 + c * 32 + srow;
    if (CVT) bw[c] = wdb + row * FDIM + sub * 8;
    else     bw32[c] = wd32 + row * FDIM + sub * 8;
  }

  int wave = tid >> 6, lane = tid & 63;
  int wm = wave >> 1, wn = wave & 1;
  int lrow = lane & 15, quad = lane >> 4;

  f32x4 acc[4][2];
#pragma unroll
  for (int i = 0; i < 4; i++)
#pragma unroll
    for (int j = 0; j < 2; j++) acc[i][j] = (f32x4){0.f, 0.f, 0.f, 0.f};

  const short* arp = Hs + (wm * 64 + lrow) * 64 + quad * 8;
  const short* brp = Bs + (wn * 32 + lrow) * 64 + quad * 8;

#pragma unroll 1
  for (int k0 = 0; k0 < FDIM; k0 += 64) {
#pragma unroll
    for (int c = 0; c < 4; c++) async16(Hs + c * 2048 + tid * 8, ah[c] + k0);
    if (CVT) {
#pragma unroll
      for (int c = 0; c < 2; c++) async16(Bs + c * 2048 + tid * 8, bw[c] + k0);
    } else {
#pragma unroll
      for (int c = 0; c < 2; c++) {
        float4 b0 = *(const float4*)(bw32[c] + k0);
        float4 b1 = *(const float4*)(bw32[c] + k0 + 4);
        short8 bsv;
        bsv[0] = f2b(b0.x); bsv[1] = f2b(b0.y); bsv[2] = f2b(b0.z); bsv[3] = f2b(b0.w);
        bsv[4] = f2b(b1.x); bsv[5] = f2b(b1.y); bsv[6] = f2b(b1.z); bsv[7] = f2b(b1.w);
        *(short8*)(Bs + c * 2048 + tid * 8) = bsv;
      }
    }
    __syncthreads();
#pragma unroll
    for (int s = 0; s < 2; s++) {
      short8 af[4], bf[2];
#pragma unroll
      for (int i = 0; i < 4; i++) af[i] = *(const short8*)(arp + i * 16 * 64 + s * 32);
#pragma unroll
      for (int j = 0; j < 2; j++) bf[j] = *(const short8*)(brp + j * 16 * 64 + s * 32);
#pragma unroll
      for (int i = 0; i < 4; i++)
#pragma unroll
        for (int j = 0; j < 2; j++)
          acc[i][j] = __builtin_amdgcn_mfma_f32_16x16x32_bf16(af[i], bf[j], acc[i][j], 0, 0, 0);
    }
    __syncthreads();
  }

#pragma unroll
  for (int i = 0; i < 4; i++) {
#pragma unroll
    for (int reg = 0; reg < 4; reg++) {
      int r = wm * 64 + i * 16 + quad * 4 + reg;
      if (r < nrows) {
        int t = rowtok[r];
#pragma unroll
        for (int j = 0; j < 2; j++)
          atomicAdd(&out[(size_t)t * DIM + d0 + wn * 32 + j * 16 + lrow], acc[i][j][reg]);
      }
    }
  }
}

extern "C" void kernel_launch(void* const* d_in, const int* in_sizes, int n_in,
                              void* d_out, int out_size, void* d_ws, size_t ws_size,
                              hipStream_t stream)
{
  const float* x  = (const float*)d_in[0];
  const float* gw = (const float*)d_in[1];
  const float* wg = (const float*)d_in[2];
  const float* wu = (const float*)d_in[3];
  const float* wd = (const float*)d_in[4];
  float* out = (float*)d_out;
  float* logits_out = out + (size_t)T_TOK * DIM;

  char* ws = (char*)d_ws;
  float* topkw   = (float*)(ws + 0);                 // 16 KiB
  int*   topke   = (int*)(ws + 16384);               // 16 KiB
  int*   counts  = (int*)(ws + 32768);
  int*   offsets = (int*)(ws + 32832);
  int*   cursors = (int*)(ws + 32896);
  int*   ntiles  = (int*)(ws + 32960);
  int4*  tiles   = (int4*)(ws + 33024);              // 640 B
  int*   perm    = (int*)(ws + 36864);               // 16 KiB, ends 53248
  // Non-overlapping big buffers (exact byte offsets):
  unsigned short* xb  = (unsigned short*)(ws + 65536);       // + 8,388,608  -> ends   8,454,144
  unsigned short* H   = (unsigned short*)(ws + 8454144);     // + 8,650,752  -> ends  17,104,896
  unsigned short* wgb = (unsigned short*)(ws + 17104896);    // +33,554,432  -> ends  50,659,328
  unsigned short* wub = (unsigned short*)(ws + 50659328);    // +33,554,432  -> ends  84,213,760
  unsigned short* wdb = (unsigned short*)(ws + 84213760);    // +33,554,432  -> ends 117,768,192
  const bool cvt1 = ws_size >= (size_t)84213760;    // wg+wu bf16 copies fit
  const bool cvt2 = ws_size >= (size_t)117768192;   // wd bf16 copy also fits
  // ws_size constant per session -> identical launch sequence every call (graph-safe)

  hipMemsetAsync(d_out, 0, (size_t)out_size * sizeof(float), stream);
  hipMemsetAsync(counts, 0, 64, stream);

  cvt_k<<<(T_TOK * DIM) / 2048, 256, 0, stream>>>(x, xb);
  if (cvt1) {
    cvt_k<<<(NE * FDIM * DIM) / 2048, 256, 0, stream>>>(wg, wgb);
    cvt_k<<<(NE * FDIM * DIM) / 2048, 256, 0, stream>>>(wu, wub);
  }
  if (cvt2) {
    cvt_k<<<(NE * DIM * FDIM) / 2048, 256, 0, stream>>>(wd, wdb);
  }
  router_k<<<T_TOK / 4, 256, 0, stream>>>(x, gw, topkw, topke, counts, logits_out);
  scan_k<<<1, 64, 0, stream>>>(counts, offsets, cursors, tiles, ntiles);
  scatter_k<<<(T_TOK * 2) / 256, 256, 0, stream>>>(topke, cursors, perm);
  if (cvt1) {
    gemm1_k<true><<<dim3(MAXTILES, FDIM / 64), 256, 0, stream>>>(
        xb, wgb, wub, nullptr, nullptr, perm, topkw, tiles, ntiles, H);
  } else {
    gemm1_k<false><<<dim3(MAXTILES, FDIM / 64), 256, 0, stream>>>(
        xb, nullptr, nullptr, wg, wu, perm, topkw, tiles, ntiles, H);
  }
  if (cvt2) {
    gemm2_k<true><<<dim3(MAXTILES, DIM / 64), 256, 0, stream>>>(
        H, wdb, nullptr, perm, tiles, ntiles, out);
  } else {
    gemm2_k<false><<<dim3(MAXTILES, DIM / 64), 256, 0, stream>>>(
        H, nullptr, wd, perm, tiles, ntiles, out);
  }
}